// Round 7
// baseline (192.006 us; speedup 1.0000x reference)
//
#include <hip/hip_runtime.h>

// TensorTrain: out[b] = first(x0) . M0(x1) . ... . M29(x30) . last(x31)
// with R=16, D=32, B=262144, selection bits in {0,1}.
//
// SINGLE-DISPATCH direct chain. Rounds 0-6 established the cost model
//   dur ~= 45 (harness poison fill) + ~6/dispatch + kernel content,
// with the meet-in-the-middle table pipeline stuck at content ~54 us
// (build ~40 sitting just under the 45-us fill cutoff in top-5, gather
// ~14, plus an 8 MB table round-trip). The direct chain's content is
// smaller than the table path's: 30 chained 16x16 matvecs per element
// = 4.06 GFLOP total = 25.8 us at the 157 TF fp32 vector ceiling, one
// dispatch, no workspace traffic at all.
//
// Key implementation points (lessons from earlier rounds):
//  - cores staged in LDS bit-deinterleaved as [core][bit][r*16+s]: a
//    wave's matvec row reads touch <=2 distinct 64 B addresses (the two
//    bit planes) -> 2-way LDS aliasing = free (m136). 60 KB/block ->
//    2 blocks/CU, 8 waves/CU: enough TLP for a VALU-bound loop.
//  - 30-step loop ROLLED around one fully-unrolled 16x16 matvec
//    (~3 KB body): round 2 proved 90 KB straight-line bodies are
//    instruction-fetch-bound (7% VALUBusy).
//  - inner matvec unrolled so v[]/nv[] stay statically indexed in VGPRs
//    (rule #20: runtime-indexed arrays spill to scratch).
//  - X read as int4 (coalesced 128 B/lane-group), bits packed MSB-first
//    into one u32; per-step bit select is a shift+mask on a register.

#define R 16
#define TT_D 32
#define BATCH 262144

// u (registers, row-vec) = u @ M, M row-major 16x16 in LDS.
__device__ __forceinline__ void rowvec_mat(const float* __restrict__ M,
                                           float* __restrict__ u) {
    float nv[R];
    #pragma unroll
    for (int s = 0; s < R; s++) nv[s] = 0.f;
    #pragma unroll
    for (int t2 = 0; t2 < R; t2++) {
        const float a = u[t2];
        #pragma unroll
        for (int s = 0; s < R; s++) nv[s] += a * M[t2 * 16 + s];
    }
    #pragma unroll
    for (int s = 0; s < R; s++) u[s] = nv[s];
}

// Pack one element's 32 bits MSB-first into a u32 (x0 at bit 31).
__device__ __forceinline__ unsigned pack_elem(const int* __restrict__ X, int b) {
    const int4* Xr = (const int4*)(X + (size_t)b * TT_D);
    unsigned v = 0;
    #pragma unroll
    for (int q = 0; q < 8; q++) {
        const int4 c = Xr[q];
        v = (v << 4) | ((unsigned)(c.x & 1) << 3) | ((unsigned)(c.y & 1) << 2)
                     | ((unsigned)(c.z & 1) << 1) | (unsigned)(c.w & 1);
    }
    return v;
}

// ---------------------------------------------------------------------------
// One thread per batch element: full 30-step chain from LDS.
__global__ __launch_bounds__(256) void tt_chain(const int* __restrict__ X,
                                                const float* __restrict__ cf,
                                                const float* __restrict__ cm,
                                                const float* __restrict__ cl,
                                                float* __restrict__ out) {
    __shared__ float scm[30 * 512];     // 60 KB: all 30 cores, bit-deinterleaved
    const int t = threadIdx.x;

    // ---- stage cores: coalesced float2 loads, split bit planes ----
    {
        const float2* cm2 = (const float2*)cm;
        for (int j = t; j < 30 * 256; j += 256) {
            const float2 vv = cm2[j];
            const int ci = j >> 8, idx = j & 255;
            scm[ci * 512 + idx] = vv.x;           // bit-0 plane
            scm[ci * 512 + 256 + idx] = vv.y;     // bit-1 plane
        }
    }

    // ---- read own element's bits (overlaps staging latency) ----
    const int b = blockIdx.x * 256 + t;
    const unsigned bits = pack_elem(X, b);

    __syncthreads();

    // ---- v = first(x0) ----
    float v[R];
    const int x0 = (int)(bits >> 31);
    #pragma unroll
    for (int r = 0; r < R; r++) v[r] = cf[r * 2 + x0];

    // ---- 30 chained matvecs; bit for core i-1 is x_i at position 31-i ----
    for (int i = 1; i <= 30; i++) {
        const float* M = scm + (i - 1) * 512 + (((bits >> (31 - i)) & 1) << 8);
        rowvec_mat(M, v);
    }

    // ---- out = v . last(x31) ----
    const int xl = (int)(bits & 1);
    float acc = 0.f;
    #pragma unroll
    for (int r = 0; r < R; r++) acc += v[r] * cl[r * 2 + xl];
    out[b] = acc;
}

extern "C" void kernel_launch(void* const* d_in, const int* in_sizes, int n_in,
                              void* d_out, int out_size, void* d_ws, size_t ws_size,
                              hipStream_t stream) {
    const int* X = (const int*)d_in[0];
    const float* cf = (const float*)d_in[1];
    const float* cm = (const float*)d_in[2];
    const float* cl = (const float*)d_in[3];
    float* out = (float*)d_out;
    (void)d_ws; (void)ws_size;          // no workspace: single dispatch

    tt_chain<<<BATCH / 256, 256, 0, stream>>>(X, cf, cm, cl, out);
}

// Round 8
// 112.815 us; speedup vs baseline: 1.7019x; 1.7019x over previous
//
#include <hip/hip_runtime.h>

// TensorTrain: out[b] = first(x0) . M0(x1) . ... . M29(x30) . last(x31)
// with R=16, D=32, B=262144, selection bits in {0,1}.
//
// Meet-in-the-middle: V16[p] (prefix row-vec) . W16[s] (suffix col-vec).
// tt_build: 512 blocks x 256 threads, block h<256 -> V16 slice, else W16.
// This is the session optimum (111.4 us), reverted after the round-7
// direct-chain experiment (192 us: per-thread matvec from LDS is
// LDS-return-bandwidth-bound — every lane pulls the full 1 KB matrix per
// step through the 128 B/cy register port).
//
// Session cost model (rounds 0-7):
//   dur ~= 90 us harness poison-fills (74% HBM peak, not ours)
//        + ~6 us per dispatch + ~15-20 us overlap-saturated content.
//   2 dispatches is optimal: grid.sync costs ~130 us on 8 XCDs (r5);
//   3/4 dispatches cost +6/+12 (r4/r0); content shuffles are ±0.4 (r6).
// Kernel-content lessons: rolled outer loops around ONE unrolled 16x16
// matvec (90 KB straight-line bodies are I-fetch-bound, r2); cores staged
// in LDS bit-deinterleaved [core][bit][256] so chain reads touch <=2
// distinct addresses per wave (broadcast, conflict-free, r3).

#define R 16
#define TT_D 32
#define BATCH 262144

// workspace layout, in floats (only the final 16-bit tables)
#define OFF_V16  0                      // 65536 x 16  (4 MB)
#define OFF_W16  1048576                // 65536 x 16  (4 MB)
#define WS_FLOATS 2097152               // 8 MB

// LDS padding: nibble-table stride 268 floats (268 % 32 = 12 -> the 4
// distinct rows a wave touches land on distinct banks; 256 would be 4-way).
#define MSTRIDE 268
#define VSTRIDE 17

// u (registers, row-vec) = u @ M, M row-major 16x16 in LDS.
// Inner fully unrolled: static indexing keeps u/nv in VGPRs.
__device__ __forceinline__ void rowvec_mat(const float* __restrict__ M,
                                           float* __restrict__ u) {
    float nv[R];
    #pragma unroll
    for (int s = 0; s < R; s++) nv[s] = 0.f;
    #pragma unroll
    for (int t2 = 0; t2 < R; t2++) {
        const float a = u[t2];
        #pragma unroll
        for (int s = 0; s < R; s++) nv[s] += a * M[t2 * 16 + s];
    }
    #pragma unroll
    for (int s = 0; s < R; s++) u[s] = nv[s];
}

// w (registers, col-vec) = M @ w.
__device__ __forceinline__ void mat_colvec(const float* __restrict__ M,
                                           float* __restrict__ w) {
    float nw[R];
    #pragma unroll
    for (int r2 = 0; r2 < R; r2++) {
        float a = 0.f;
        #pragma unroll
        for (int k = 0; k < R; k++) a += M[r2 * 16 + k] * w[k];
        nw[r2] = a;
    }
    #pragma unroll
    for (int r2 = 0; r2 < R; r2++) w[r2] = nw[r2];
}

// Row r of M[lbase](b0) @ M[lbase+1](b1) @ M[lbase+2](b2) @ M[lbase+3](b3),
// bits of e MSB-first. scm layout: [core][bit][r*16+s], 512 floats/core.
__device__ __forceinline__ void chain4_row(const float* __restrict__ scm, int lbase,
                                           int e, int r, float* __restrict__ u) {
    const float* M0 = scm + lbase * 512 + ((e >> 3) & 1) * 256;
    #pragma unroll
    for (int s = 0; s < R; s++) u[s] = M0[r * 16 + s];
    for (int k = 1; k <= 3; k++) {
        const float* M = scm + (lbase + k) * 512 + ((e >> (3 - k)) & 1) * 256;
        rowvec_mat(M, u);
    }
}

// ---------------------------------------------------------------------------
__global__ __launch_bounds__(256) void tt_build(const float* __restrict__ cf,
                                                const float* __restrict__ cm,
                                                const float* __restrict__ cl,
                                                float* __restrict__ ws) {
    __shared__ float scm[15 * 512];     // staged cores, bit-deinterleaved (30 KB)
    __shared__ float T0[16 * MSTRIDE];  // prefix: B=M7..10 ; suffix: F=M23..26
    __shared__ float T1[16 * MSTRIDE];  // prefix: C=M11..14; suffix: W4 vecs (VSTRIDE)
    __shared__ float SA[16 * VSTRIDE];  // suffix: Dm[h>>4] rows
    __shared__ float SE[16 * VSTRIDE];  // suffix: E[h&15] rows
    __shared__ float SV[16];            // prefix: v8 = first@M0..M6
    __shared__ float SG[256];           // suffix: G = Dm @ E

    const int t = threadIdx.x;
    const int e = t >> 4, r = t & 15;
    const bool isPrefix = (blockIdx.x < 256);
    const int h = isPrefix ? blockIdx.x : (blockIdx.x - 256);

    // ---- phase 0: stage this half's 15 cores into LDS, bit-deinterleaved ----
    {
        const float2* cm2 = (const float2*)(cm + (isPrefix ? 0 : 15) * 512);
        for (int j = t; j < 15 * 256; j += 256) {
            const float2 vv = cm2[j];                 // coalesced 8B loads
            const int ci = j >> 8, idx = j & 255;
            scm[ci * 512 + idx] = vv.x;               // bit 0 plane
            scm[ci * 512 + 256 + idx] = vv.y;         // bit 1 plane
        }
    }
    __syncthreads();

    if (isPrefix) {
        // ---- phase 1a: wave0 lanes 0-15, column-parallel v8 chain ----
        // v8 = first(x0).M0(x1)...M6(x7), x0 = h>>7, M_j bit = (h>>(6-j))&1.
        if (t < 16) {
            SV[t] = cf[t * 2 + ((h >> 7) & 1)];
            for (int j = 0; j < 7; j++) {
                const float* M = scm + j * 512 + (((h >> (6 - j)) & 1) << 8);
                float a = 0.f;
                #pragma unroll
                for (int t2 = 0; t2 < R; t2++) a += SV[t2] * M[t2 * 16 + t];
                SV[t] = a;   // single wave: all lane reads precede this write
            }
        }
        // ---- phase 1b: nibble tables B (x8..11) -> T0, C (x12..15) -> T1 ----
        {
            float u[R];
            for (int tab = 0; tab < 2; tab++) {
                chain4_row(scm, 7 + 4 * tab, e, r, u);
                float* dst = (tab ? T1 : T0) + e * MSTRIDE + r * 16;
                #pragma unroll
                for (int s = 0; s < R; s++) dst[s] = u[s];
            }
        }
        __syncthreads();
        // ---- phase 2: V16[h*256+t] = v8 @ B[t>>4] @ C[t&15] ----
        float v[R];
        #pragma unroll
        for (int k = 0; k < R; k++) v[k] = SV[k];     // broadcast
        const float* src = T0 + (t >> 4) * MSTRIDE;
        for (int q = 0; q < 2; q++) {
            rowvec_mat(src, v);
            src = T1 + (t & 15) * MSTRIDE;
        }
        float* o = ws + OFF_V16 + (size_t)(h * 256 + t) * 16;
        #pragma unroll
        for (int s = 0; s < R; s++) o[s] = v[s];
    } else {
        // local core index = global - 15: Dm(M15..18)=0, E(M19..22)=4,
        // F(M23..26)=8, M27..29 -> 12..14.
        // ---- phase 1: F rows by all threads; Dm/E rows by t in [16,48);
        //               W4 vectors by t in [48,64) ----
        {
            float u[R];
            for (int job = 0; job < 2; job++) {
                int lb, ee, rr;
                float* dst;
                bool active = true;
                if (job == 0)      { lb = 8; ee = e;      rr = r;      dst = T0 + e * MSTRIDE + r * 16; }
                else if (t < 16)   { lb = 0; ee = h >> 4; rr = t;      dst = SA + t * VSTRIDE; }
                else if (t < 32)   { lb = 4; ee = h & 15; rr = t - 16; dst = SE + (t - 16) * VSTRIDE; }
                else               { active = false; lb = 0; ee = 0; rr = 0; dst = nullptr; }
                if (active) {
                    chain4_row(scm, lb, ee, rr, u);
                    #pragma unroll
                    for (int s = 0; s < R; s++) dst[s] = u[s];
                }
            }
        }
        if (t >= 48 && t < 64) {                      // W4[l] = M27(l3)M28(l2)M29(l1).last(l0)
            const int l = t - 48;
            float w[R];
            #pragma unroll
            for (int r2 = 0; r2 < R; r2++) w[r2] = cl[r2 * 2 + (l & 1)];
            for (int k = 0; k < 3; k++) {             // M29, M28, M27
                const float* M = scm + (14 - k) * 512 + (((l >> (k + 1)) & 1) << 8);
                mat_colvec(M, w);
            }
            float* dst = T1 + l * VSTRIDE;
            #pragma unroll
            for (int r2 = 0; r2 < R; r2++) dst[r2] = w[r2];
        }
        __syncthreads();
        // ---- phase 2: G = Dm[h>>4] @ E[h&15] (one element per thread) ----
        {
            const int gr = t >> 4, gc = t & 15;
            float a = 0.f;
            #pragma unroll
            for (int k = 0; k < R; k++) a += SA[gr * VSTRIDE + k] * SE[k * VSTRIDE + gc];
            SG[gr * 16 + gc] = a;
        }
        __syncthreads();
        // ---- phase 3: W16[h*256+t] = G @ (F[t>>4] @ W4[t&15]) ----
        float w[R];
        #pragma unroll
        for (int k = 0; k < R; k++) w[k] = T1[(t & 15) * VSTRIDE + k];
        const float* src = T0 + (t >> 4) * MSTRIDE;
        for (int q = 0; q < 2; q++) {
            mat_colvec(src, w);
            src = SG;
        }
        float* o = ws + OFF_W16 + (size_t)(h * 256 + t) * 16;
        #pragma unroll
        for (int r2 = 0; r2 < R; r2++) o[r2] = w[r2];
    }
}

// ---------------------------------------------------------------------------
// Main: one thread per batch element: 128B X read, two 64B table gathers,
// 16-wide dot.
__global__ __launch_bounds__(256) void tt_main(const int* __restrict__ X,
                                               const float* __restrict__ ws,
                                               float* __restrict__ out) {
    const int b = blockIdx.x * 256 + threadIdx.x;
    const int4* Xr = (const int4*)(X + (size_t)b * TT_D);
    int xv[TT_D];
    #pragma unroll
    for (int q = 0; q < 8; q++) {
        int4 c = Xr[q];
        xv[q * 4 + 0] = c.x; xv[q * 4 + 1] = c.y; xv[q * 4 + 2] = c.z; xv[q * 4 + 3] = c.w;
    }
    unsigned p = 0, s = 0;
    #pragma unroll
    for (int i = 0; i < 16; i++) p = (p << 1) | (unsigned)(xv[i] & 1);
    #pragma unroll
    for (int i = 16; i < 32; i++) s = (s << 1) | (unsigned)(xv[i] & 1);

    const float4* v = (const float4*)(ws + OFF_V16 + (size_t)p * 16);
    const float4* w = (const float4*)(ws + OFF_W16 + (size_t)s * 16);
    float acc = 0.f;
    #pragma unroll
    for (int k = 0; k < 4; k++) {
        float4 a = v[k], c = w[k];
        acc += a.x * c.x + a.y * c.y + a.z * c.z + a.w * c.w;
    }
    out[b] = acc;
}

// ---------------------------------------------------------------------------
// Fallback: direct per-thread chain (used only if ws too small).
__global__ __launch_bounds__(256) void tt_direct(const int* __restrict__ X,
                                                 const float* __restrict__ cf,
                                                 const float* __restrict__ cm,
                                                 const float* __restrict__ cl,
                                                 float* __restrict__ out) {
    __shared__ float scm[30 * 16 * 16 * 2];
    for (int i = threadIdx.x; i < 30 * 16 * 16 * 2; i += blockDim.x) scm[i] = cm[i];
    __syncthreads();
    const int b = blockIdx.x * blockDim.x + threadIdx.x;
    if (b >= BATCH) return;
    const int* xr = X + (size_t)b * TT_D;
    float v[R], nv[R];
    const int x0 = xr[0] & 1;
    #pragma unroll
    for (int rr = 0; rr < R; rr++) v[rr] = cf[rr * 2 + x0];
    for (int i = 1; i <= 30; i++) {
        const int bit = xr[i] & 1;
        const float* M = scm + (i - 1) * 512;
        #pragma unroll
        for (int s2 = 0; s2 < R; s2++) {
            float acc = 0.f;
            #pragma unroll
            for (int rr = 0; rr < R; rr++) acc += v[rr] * M[(rr * 16 + s2) * 2 + bit];
            nv[s2] = acc;
        }
        #pragma unroll
        for (int s2 = 0; s2 < R; s2++) v[s2] = nv[s2];
    }
    const int xl = xr[31] & 1;
    float acc = 0.f;
    #pragma unroll
    for (int rr = 0; rr < R; rr++) acc += v[rr] * cl[rr * 2 + xl];
    out[b] = acc;
}

extern "C" void kernel_launch(void* const* d_in, const int* in_sizes, int n_in,
                              void* d_out, int out_size, void* d_ws, size_t ws_size,
                              hipStream_t stream) {
    const int* X = (const int*)d_in[0];
    const float* cf = (const float*)d_in[1];
    const float* cm = (const float*)d_in[2];
    const float* cl = (const float*)d_in[3];
    float* out = (float*)d_out;

    if (ws_size >= (size_t)WS_FLOATS * sizeof(float)) {
        float* ws = (float*)d_ws;
        tt_build<<<512, 256, 0, stream>>>(cf, cm, cl, ws);
        tt_main<<<BATCH / 256, 256, 0, stream>>>(X, ws, out);
    } else {
        tt_direct<<<(BATCH + 255) / 256, 256, 0, stream>>>(X, cf, cm, cl, out);
    }
}